// Round 7
// baseline (3272.904 us; speedup 1.0000x reference)
//
#include <hip/hip_runtime.h>
#include <cstdint>

#define NPTS 8192
#define NBATCH 4
#define NS 2048
#define NK 32
#define CIN 64
#define C0 67   // 3 + 64
#define H1 64
#define H2 64
#define H3 128
#define CAP 1024
#define BIGF 1e10f

// ws layout in floats
#define WT0_OFF 0        // 67*64
#define B0_OFF  4288     // 64
#define WT1_OFF 4352     // 64*64
#define B1_OFF  8448     // 64
#define WT2_OFF 8512     // 64*128
#define B2_OFF  16704    // 128
#define FPS_OFF 16832    // NBATCH*NS ints from here

__device__ __forceinline__ float sq3(float ax, float ay, float az) {
  // exact f32, no contraction: (ax*ax + ay*ay) + az*az
  return __fadd_rn(__fadd_rn(__fmul_rn(ax, ax), __fmul_rn(ay, ay)), __fmul_rn(az, az));
}

// VALU-speed cross-lane fmax via DPP (ctrl must be an immediate)
#define DPPMAX(r, ctrl)                                                              \
  {                                                                                  \
    int _t = __builtin_amdgcn_update_dpp(__float_as_int(r), __float_as_int(r),       \
                                         (ctrl), 0xf, 0xf, true);                    \
    (r) = fmaxf((r), __int_as_float(_t));                                            \
  }

// ---------------- fold BN into weights (transposed [c][o]) ----------------
__global__ void fold_kernel(const float* __restrict__ W0, const float* __restrict__ g0, const float* __restrict__ be0, const float* __restrict__ m0, const float* __restrict__ v0,
                            const float* __restrict__ W1, const float* __restrict__ g1, const float* __restrict__ be1, const float* __restrict__ m1, const float* __restrict__ v1,
                            const float* __restrict__ W2, const float* __restrict__ g2, const float* __restrict__ be2, const float* __restrict__ m2, const float* __restrict__ v2,
                            float* __restrict__ ws) {
  int t = blockIdx.x * 256 + threadIdx.x;
  if (t < C0 * H1) {
    int c = t / H1, o = t - c * H1;
    float sc = g0[o] / sqrtf(v0[o] + 1e-5f);
    ws[WT0_OFF + t] = W0[o * C0 + c] * sc;
  } else if (t < B0_OFF + H1) {
    int o = t - B0_OFF;
    float sc = g0[o] / sqrtf(v0[o] + 1e-5f);
    ws[t] = be0[o] - m0[o] * sc;
  } else if (t < WT1_OFF + H1 * H2) {
    int t2 = t - WT1_OFF; int c = t2 / H2, o = t2 - c * H2;
    float sc = g1[o] / sqrtf(v1[o] + 1e-5f);
    ws[t] = W1[o * H1 + c] * sc;
  } else if (t < B1_OFF + H2) {
    int o = t - B1_OFF;
    float sc = g1[o] / sqrtf(v1[o] + 1e-5f);
    ws[t] = be1[o] - m1[o] * sc;
  } else if (t < WT2_OFF + H2 * H3) {
    int t2 = t - WT2_OFF; int c = t2 / H3, o = t2 - c * H3;
    float sc = g2[o] / sqrtf(v2[o] + 1e-5f);
    ws[t] = W2[o * H2 + c] * sc;
  } else if (t < B2_OFF + H3) {
    int o = t - B2_OFF;
    float sc = g2[o] / sqrtf(v2[o] + 1e-5f);
    ws[t] = be2[o] - m2[o] * sc;
  }
}

// ---------------- FPS: one block per batch, 512 threads, 16 pts/thread ----------------
// Zero VMEM ops in the serial loop: outputs buffered in LDS, flushed at the end.
// DPP reduces; winner fields via v_readlane. Tie-break == reference lowest-index.
__global__ __launch_bounds__(512)
void fps_kernel(const float* __restrict__ xyz, float* __restrict__ newxyz, int* __restrict__ fpsidx) {
  const int b = blockIdx.x;
  const float* px = xyz + (size_t)b * NPTS * 3;
  const int tid = threadIdx.x;
  const int lane = tid & 63;
  const int wv = tid >> 6;   // 0..7

  float X[16], Y[16], Z[16], D[16];
#pragma unroll
  for (int j = 0; j < 16; ++j) {
    int p = tid * 16 + j;
    X[j] = px[p * 3 + 0];
    Y[j] = px[p * 3 + 1];
    Z[j] = px[p * 3 + 2];
    D[j] = BIGF;
  }

  // candidate slots: [parity][wave][8 floats: d, idx_bits, x, y, z, pad...]
  __shared__ float cnd[2][8][8];
  // output staging (flushed after the loop): 24 KB + 8 KB
  __shared__ float oX[NS], oY[NS], oZ[NS];
  __shared__ int oI[NS];

  float cx = px[0], cy = px[1], cz = px[2];
  if (tid == 0) {
    oI[0] = 0; oX[0] = cx; oY[0] = cy; oZ[0] = cz;
  }

  int par = 0;
  for (int t = 1; t < NS; ++t) {
    // ---- min-dist update (exact f32, reference op order); D doubles as nd ----
#pragma unroll
    for (int j = 0; j < 16; ++j) {
      float dx = __fsub_rn(X[j], cx);
      float dy = __fsub_rn(Y[j], cy);
      float dz = __fsub_rn(Z[j], cz);
      float d = sq3(dx, dy, dz);
      D[j] = fminf(D[j], d);
    }
    // balanced fmax tree (exact max value; order-independent for non-NaN)
    float q0 = fmaxf(fmaxf(D[0], D[1]), fmaxf(D[2], D[3]));
    float q1 = fmaxf(fmaxf(D[4], D[5]), fmaxf(D[6], D[7]));
    float q2 = fmaxf(fmaxf(D[8], D[9]), fmaxf(D[10], D[11]));
    float q3 = fmaxf(fmaxf(D[12], D[13]), fmaxf(D[14], D[15]));
    float bd = fmaxf(fmaxf(q0, q1), fmaxf(q2, q3));

    // ---- wave max via DPP: 4x row_ror -> row max; bcast15/31 -> lane63 = wave max ----
    float r = bd;
    DPPMAX(r, 0x121);  // row_ror:1
    DPPMAX(r, 0x122);  // row_ror:2
    DPPMAX(r, 0x124);  // row_ror:4
    DPPMAX(r, 0x128);  // row_ror:8   -> every lane holds its 16-lane row max
    DPPMAX(r, 0x142);  // row_bcast15 -> lane31=max(r0,r1), lane63=max(r2,r3)
    DPPMAX(r, 0x143);  // row_bcast31 -> lane63 = wave max
    float bdw = __int_as_float(__builtin_amdgcn_readlane(__float_as_int(r), 63));

    unsigned long long mk = __ballot(bd == bdw);
    int wl = __ffsll(mk) - 1;   // lowest lane = lowest index range
    if (lane == wl) {
      // lowest j with D[j]==bdw, static indexing only
      int bj = 15;
      float sx = X[15], sy = Y[15], sz = Z[15];
#pragma unroll
      for (int j = 14; j >= 0; --j) {
        bool e = (D[j] == bdw);
        bj = e ? j : bj;
        sx = e ? X[j] : sx;
        sy = e ? Y[j] : sy;
        sz = e ? Z[j] : sz;
      }
      float* c = &cnd[par][wv][0];
      c[0] = bdw;
      c[1] = __int_as_float(tid * 16 + bj);
      c[2] = sx; c[3] = sy; c[4] = sz;
    }
    __syncthreads();

    // ---- cross-wave reduce: lanes mirror the 8 candidates, DPP ring-max over 16 ----
    const int ci = lane & 7;
    float4 cd = *(const float4*)&cnd[par][ci][0];   // d, idx_bits, x, y
    float czv = cnd[par][ci][4];
    float rr = cd.x;
    DPPMAX(rr, 0x121);
    DPPMAX(rr, 0x122);
    DPPMAX(rr, 0x124);
    DPPMAX(rr, 0x128);   // every lane: max over the 8 candidates (16-ring w/ duplicates)
    unsigned long long wm = __ballot(cd.x == rr) & 0xFFull;
    int ww = __ffsll(wm) - 1;   // lowest wave = lowest point-index range
    cx = __int_as_float(__builtin_amdgcn_readlane(__float_as_int(cd.z), ww));
    cy = __int_as_float(__builtin_amdgcn_readlane(__float_as_int(cd.w), ww));
    cz = __int_as_float(__builtin_amdgcn_readlane(__float_as_int(czv), ww));
    if (tid == 0) {
      int far = __builtin_amdgcn_readlane(__float_as_int(cd.y), ww);
      oI[t] = far; oX[t] = cx; oY[t] = cy; oZ[t] = cz;
    }
    par ^= 1;
  }
  __syncthreads();

  // ---- cooperative flush: LDS -> global (coalesced enough; off the serial path) ----
  for (int i = tid; i < NS; i += 512) {
    fpsidx[b * NS + i] = oI[i];
    float* o = newxyz + ((size_t)b * NS + i) * 3;
    o[0] = oX[i]; o[1] = oY[i]; o[2] = oZ[i];
  }
}

// ---------------- ball query + group + MLP + maxpool: one block per centroid ----------------
__global__ __launch_bounds__(256)
void sa_kernel(const float* __restrict__ xyz, const float* __restrict__ feat,
               const float* __restrict__ ws, const int* __restrict__ fpsidx,
               const float* __restrict__ newxyz, float* __restrict__ outf) {
  const int bs = blockIdx.x;
  const int b = bs >> 11;
  const int s = bs & (NS - 1);
  const int tid = threadIdx.x;

  __shared__ unsigned long long cand[CAP];
  __shared__ int cntS;
  __shared__ int sel[NK];
  __shared__ float hA[32 * 69];
  __shared__ float hB[32 * 65];

  const float* px = xyz + (size_t)b * NPTS * 3;
  const float* pf = feat + (size_t)b * NPTS * CIN;
  const size_t srow = (size_t)b * NS + s;
  const float cx = newxyz[srow * 3 + 0];
  const float cy = newxyz[srow * 3 + 1];
  const float cz = newxyz[srow * 3 + 2];

  if (tid == 0) cntS = 0;
  __syncthreads();

  // ---- phase A: ball query (reference formula, exact f32, no contraction) ----
  const float ssrc = sq3(cx, cy, cz);
  const float R2F = 0.04f;  // f32 round of f64 0.2**2 (NOT 0.2f*0.2f — 1 ulp above)
  for (int p = tid; p < NPTS; p += 256) {
    float x = px[p * 3 + 0], y = px[p * 3 + 1], z = px[p * 3 + 2];
    float sdst = sq3(x, y, z);
    float dot = __fadd_rn(__fadd_rn(__fmul_rn(cx, x), __fmul_rn(cy, y)), __fmul_rn(cz, z));
    float d = __fsub_rn(__fadd_rn(ssrc, sdst), __fmul_rn(2.0f, dot));
    d = fmaxf(d, 0.0f);
    if (d <= R2F) {
      int pos = atomicAdd(&cntS, 1);
      if (pos < CAP) cand[pos] = ((unsigned long long)__float_as_uint(d) << 32) | (unsigned long long)(unsigned)p;
    }
  }
  __syncthreads();

  // ---- phase B: select 32 smallest (tie -> lower point index) by wave 0 ----
  if (tid < 64) {
    const int cnt = min(cntS, CAP);
    unsigned long long key[CAP / 64];
#pragma unroll
    for (int r = 0; r < CAP / 64; ++r) {
      int e = r * 64 + tid;
      key[r] = (e < cnt) ? cand[e] : ~0ull;
    }
    unsigned long long thr = 0ull;  // keys are unique; extract in strictly increasing order
    int firstidx = 0;
    for (int j = 0; j < NK; ++j) {
      unsigned long long bk = ~0ull;
#pragma unroll
      for (int r = 0; r < CAP / 64; ++r) {
        unsigned long long kk = key[r];
        bool ok = (kk >= thr) && (kk < bk);
        bk = ok ? kk : bk;
      }
#pragma unroll
      for (int m = 1; m < 64; m <<= 1) {
        unsigned long long o = __shfl_xor(bk, m);
        bk = (o < bk) ? o : bk;
      }
      if (j == 0) firstidx = (int)(bk & 0xffffffffull);
      int idx = (bk == ~0ull) ? firstidx : (int)(bk & 0xffffffffull);  // pad with nearest (ref semantics)
      if (tid == 0) sel[j] = idx;
      if (bk != ~0ull) thr = bk + 1ull;
    }
  }
  __syncthreads();

  // ---- phase C: build h0 = [centered xyz(3) | feat(64)] into hA [32][69] ----
  {
    int kk = tid >> 3, j = tid & 7;
    int ip = sel[kk];
    const float* fr = pf + (size_t)ip * CIN + j * 8;
    float4 a = *(const float4*)(fr);
    float4 c4 = *(const float4*)(fr + 4);
    float* hrow = hA + kk * 69 + 3 + j * 8;
    hrow[0] = a.x;  hrow[1] = a.y;  hrow[2] = a.z;  hrow[3] = a.w;
    hrow[4] = c4.x; hrow[5] = c4.y; hrow[6] = c4.z; hrow[7] = c4.w;
  }
  if (tid < 32) {
    int ip = sel[tid];
    hA[tid * 69 + 0] = px[ip * 3 + 0] - cx;
    hA[tid * 69 + 1] = px[ip * 3 + 1] - cy;
    hA[tid * 69 + 2] = px[ip * 3 + 2] - cz;
  }
  __syncthreads();

  const int k = tid & 31;   // neighbor slot
  const int ob = tid >> 5;  // output-channel block (0..7)

  // ---- layer 1: 67 -> 64 ----
  {
    const float* Wt = ws + WT0_OFF;
    const float* bb = ws + B0_OFF;
    const int o0 = ob * 8;
    float acc[8];
#pragma unroll
    for (int i = 0; i < 8; ++i) acc[i] = bb[o0 + i];
    const float* hrow = hA + k * 69;
    for (int c = 0; c < C0; ++c) {
      float h = hrow[c];
      const float4 w0 = *(const float4*)(Wt + c * H1 + o0);
      const float4 w1 = *(const float4*)(Wt + c * H1 + o0 + 4);
      acc[0] = fmaf(h, w0.x, acc[0]); acc[1] = fmaf(h, w0.y, acc[1]);
      acc[2] = fmaf(h, w0.z, acc[2]); acc[3] = fmaf(h, w0.w, acc[3]);
      acc[4] = fmaf(h, w1.x, acc[4]); acc[5] = fmaf(h, w1.y, acc[5]);
      acc[6] = fmaf(h, w1.z, acc[6]); acc[7] = fmaf(h, w1.w, acc[7]);
    }
    float* orow = hB + k * 65 + o0;
#pragma unroll
    for (int i = 0; i < 8; ++i) orow[i] = fmaxf(acc[i], 0.0f);
  }
  __syncthreads();

  // ---- layer 2: 64 -> 64 (hB -> hA, stride 65) ----
  {
    const float* Wt = ws + WT1_OFF;
    const float* bb = ws + B1_OFF;
    const int o0 = ob * 8;
    float acc[8];
#pragma unroll
    for (int i = 0; i < 8; ++i) acc[i] = bb[o0 + i];
    const float* hrow = hB + k * 65;
    for (int c = 0; c < H1; ++c) {
      float h = hrow[c];
      const float4 w0 = *(const float4*)(Wt + c * H2 + o0);
      const float4 w1 = *(const float4*)(Wt + c * H2 + o0 + 4);
      acc[0] = fmaf(h, w0.x, acc[0]); acc[1] = fmaf(h, w0.y, acc[1]);
      acc[2] = fmaf(h, w0.z, acc[2]); acc[3] = fmaf(h, w0.w, acc[3]);
      acc[4] = fmaf(h, w1.x, acc[4]); acc[5] = fmaf(h, w1.y, acc[5]);
      acc[6] = fmaf(h, w1.z, acc[6]); acc[7] = fmaf(h, w1.w, acc[7]);
    }
    float* orow = hA + k * 65 + o0;
#pragma unroll
    for (int i = 0; i < 8; ++i) orow[i] = fmaxf(acc[i], 0.0f);
  }
  __syncthreads();

  // ---- layer 3: 64 -> 128 + max over neighbors ----
  {
    const float* Wt = ws + WT2_OFF;
    const float* bb = ws + B2_OFF;
    const int o0 = ob * 16;
    float acc[16];
#pragma unroll
    for (int i = 0; i < 16; ++i) acc[i] = bb[o0 + i];
    const float* hrow = hA + k * 65;
    for (int c = 0; c < H2; ++c) {
      float h = hrow[c];
      const float4 w0 = *(const float4*)(Wt + c * H3 + o0);
      const float4 w1 = *(const float4*)(Wt + c * H3 + o0 + 4);
      const float4 w2 = *(const float4*)(Wt + c * H3 + o0 + 8);
      const float4 w3 = *(const float4*)(Wt + c * H3 + o0 + 12);
      acc[0]  = fmaf(h, w0.x, acc[0]);  acc[1]  = fmaf(h, w0.y, acc[1]);
      acc[2]  = fmaf(h, w0.z, acc[2]);  acc[3]  = fmaf(h, w0.w, acc[3]);
      acc[4]  = fmaf(h, w1.x, acc[4]);  acc[5]  = fmaf(h, w1.y, acc[5]);
      acc[6]  = fmaf(h, w1.z, acc[6]);  acc[7]  = fmaf(h, w1.w, acc[7]);
      acc[8]  = fmaf(h, w2.x, acc[8]);  acc[9]  = fmaf(h, w2.y, acc[9]);
      acc[10] = fmaf(h, w2.z, acc[10]); acc[11] = fmaf(h, w2.w, acc[11]);
      acc[12] = fmaf(h, w3.x, acc[12]); acc[13] = fmaf(h, w3.y, acc[13]);
      acc[14] = fmaf(h, w3.z, acc[14]); acc[15] = fmaf(h, w3.w, acc[15]);
    }
#pragma unroll
    for (int i = 0; i < 16; ++i) acc[i] = fmaxf(acc[i], 0.0f);
    // max over 32 neighbor slots (lanes differing in bits 0..4)
#pragma unroll
    for (int m = 1; m < 32; m <<= 1) {
#pragma unroll
      for (int i = 0; i < 16; ++i) {
        float o = __shfl_xor(acc[i], m);
        acc[i] = fmaxf(acc[i], o);
      }
    }
    if (k == 0) {
      float* op = outf + srow * H3 + o0;
      *(float4*)(op + 0)  = make_float4(acc[0],  acc[1],  acc[2],  acc[3]);
      *(float4*)(op + 4)  = make_float4(acc[4],  acc[5],  acc[6],  acc[7]);
      *(float4*)(op + 8)  = make_float4(acc[8],  acc[9],  acc[10], acc[11]);
      *(float4*)(op + 12) = make_float4(acc[12], acc[13], acc[14], acc[15]);
    }
  }
}

extern "C" void kernel_launch(void* const* d_in, const int* in_sizes, int n_in,
                              void* d_out, int out_size, void* d_ws, size_t ws_size,
                              hipStream_t stream) {
  const float* xyz  = (const float*)d_in[0];
  const float* feat = (const float*)d_in[1];
  const float* W0 = (const float*)d_in[2];
  const float* g0 = (const float*)d_in[3];
  const float* be0 = (const float*)d_in[4];
  const float* m0 = (const float*)d_in[5];
  const float* v0 = (const float*)d_in[6];
  const float* W1 = (const float*)d_in[7];
  const float* g1 = (const float*)d_in[8];
  const float* be1 = (const float*)d_in[9];
  const float* m1 = (const float*)d_in[10];
  const float* v1 = (const float*)d_in[11];
  const float* W2 = (const float*)d_in[12];
  const float* g2 = (const float*)d_in[13];
  const float* be2 = (const float*)d_in[14];
  const float* m2 = (const float*)d_in[15];
  const float* v2 = (const float*)d_in[16];

  float* out = (float*)d_out;               // [B,S,3] then [B,S,128]
  float* ws = (float*)d_ws;
  int* fpsidx = (int*)(ws + FPS_OFF);
  float* outfeat = out + (size_t)NBATCH * NS * 3;

  fold_kernel<<<(B2_OFF + H3 + 255) / 256, 256, 0, stream>>>(
      W0, g0, be0, m0, v0, W1, g1, be1, m1, v1, W2, g2, be2, m2, v2, ws);
  fps_kernel<<<NBATCH, 512, 0, stream>>>(xyz, out, fpsidx);
  sa_kernel<<<NBATCH * NS, 256, 0, stream>>>(xyz, feat, ws, fpsidx, out, outfeat);
}

// Round 8
// 2867.203 us; speedup vs baseline: 1.1415x; 1.1415x over previous
//
#include <hip/hip_runtime.h>
#include <cstdint>

#define NPTS 8192
#define NBATCH 4
#define NS 2048
#define NK 32
#define CIN 64
#define C0 67   // 3 + 64
#define H1 64
#define H2 64
#define H3 128
#define CAP 1024
#define BIGF 1e10f

// ws layout in floats
#define WT0_OFF 0        // 67*64
#define B0_OFF  4288     // 64
#define WT1_OFF 4352     // 64*64
#define B1_OFF  8448     // 64
#define WT2_OFF 8512     // 64*128
#define B2_OFF  16704    // 128
#define FPS_OFF 16832    // NBATCH*NS ints from here

__device__ __forceinline__ float sq3(float ax, float ay, float az) {
  // exact f32, no contraction: (ax*ax + ay*ay) + az*az
  return __fadd_rn(__fadd_rn(__fmul_rn(ax, ax), __fmul_rn(ay, ay)), __fmul_rn(az, az));
}

// Lexicographic (max d, tie -> min idx) pair-combine with a DPP-shuffled copy.
// bound_ctrl=false + old=self: lanes not written combine with themselves (no-op).
#define PAIRRED(dv, iv, ctrl)                                                          \
  {                                                                                    \
    int _sd = __builtin_amdgcn_update_dpp(__float_as_int(dv), __float_as_int(dv),      \
                                          (ctrl), 0xf, 0xf, false);                    \
    int _si = __builtin_amdgcn_update_dpp((iv), (iv), (ctrl), 0xf, 0xf, false);        \
    float _fd = __int_as_float(_sd);                                                   \
    bool _tk = (_fd > (dv)) || ((_fd == (dv)) && (_si < (iv)));                        \
    (dv) = _tk ? _fd : (dv);                                                           \
    (iv) = _tk ? _si : (iv);                                                           \
  }

// ---------------- fold BN into weights (transposed [c][o]) ----------------
__global__ void fold_kernel(const float* __restrict__ W0, const float* __restrict__ g0, const float* __restrict__ be0, const float* __restrict__ m0, const float* __restrict__ v0,
                            const float* __restrict__ W1, const float* __restrict__ g1, const float* __restrict__ be1, const float* __restrict__ m1, const float* __restrict__ v1,
                            const float* __restrict__ W2, const float* __restrict__ g2, const float* __restrict__ be2, const float* __restrict__ m2, const float* __restrict__ v2,
                            float* __restrict__ ws) {
  int t = blockIdx.x * 256 + threadIdx.x;
  if (t < C0 * H1) {
    int c = t / H1, o = t - c * H1;
    float sc = g0[o] / sqrtf(v0[o] + 1e-5f);
    ws[WT0_OFF + t] = W0[o * C0 + c] * sc;
  } else if (t < B0_OFF + H1) {
    int o = t - B0_OFF;
    float sc = g0[o] / sqrtf(v0[o] + 1e-5f);
    ws[t] = be0[o] - m0[o] * sc;
  } else if (t < WT1_OFF + H1 * H2) {
    int t2 = t - WT1_OFF; int c = t2 / H2, o = t2 - c * H2;
    float sc = g1[o] / sqrtf(v1[o] + 1e-5f);
    ws[t] = W1[o * H1 + c] * sc;
  } else if (t < B1_OFF + H2) {
    int o = t - B1_OFF;
    float sc = g1[o] / sqrtf(v1[o] + 1e-5f);
    ws[t] = be1[o] - m1[o] * sc;
  } else if (t < WT2_OFF + H2 * H3) {
    int t2 = t - WT2_OFF; int c = t2 / H3, o = t2 - c * H3;
    float sc = g2[o] / sqrtf(v2[o] + 1e-5f);
    ws[t] = W2[o * H2 + c] * sc;
  } else if (t < B2_OFF + H3) {
    int o = t - B2_OFF;
    float sc = g2[o] / sqrtf(v2[o] + 1e-5f);
    ws[t] = be2[o] - m2[o] * sc;
  }
}

// ---------------- FPS: one block per batch, 256 threads, 32 pts/thread ----------------
// 1 wave/SIMD; inline (d,idx) argmax; pair-DPP wave reduce (exact lexicographic ties);
// cross-wave reduce = 2 pair-DPP steps over 4 candidates; coords via uniform re-load.
__global__ __launch_bounds__(256, 1)
void fps_kernel(const float* __restrict__ xyz, float* __restrict__ newxyz, int* __restrict__ fpsidx) {
  const int b = blockIdx.x;
  const float* px = xyz + (size_t)b * NPTS * 3;
  const int tid = threadIdx.x;
  const int lane = tid & 63;
  const int wv = tid >> 6;   // 0..3

  float X[32], Y[32], Z[32], D[32];
#pragma unroll
  for (int j = 0; j < 32; ++j) {
    int p = tid * 32 + j;
    X[j] = px[p * 3 + 0];
    Y[j] = px[p * 3 + 1];
    Z[j] = px[p * 3 + 2];
    D[j] = BIGF;
  }

  __shared__ float cndD[2][4];
  __shared__ int cndI[2][4];
  __shared__ float oX[NS], oY[NS], oZ[NS];
  __shared__ int oI[NS];

  float cx = px[0], cy = px[1], cz = px[2];
  if (tid == 0) { oI[0] = 0; oX[0] = cx; oY[0] = cy; oZ[0] = cz; }

  int par = 0;
  for (int t = 1; t < NS; ++t) {
    // ---- min-dist update (exact f32, reference op order) + inline (d,idx) argmax ----
    float bd = -1.0f; int bi = 0;
#pragma unroll
    for (int j = 0; j < 32; ++j) {
      float dx = __fsub_rn(X[j], cx);
      float dy = __fsub_rn(Y[j], cy);
      float dz = __fsub_rn(Z[j], cz);
      float d = sq3(dx, dy, dz);
      float nd = fminf(D[j], d);
      D[j] = nd;
      bool gt = nd > bd;          // strict >, ascending j -> lowest j kept
      bd = gt ? nd : bd;
      bi = gt ? (tid * 32 + j) : bi;
    }
    // ---- wave pair-argmax via DPP; lane63 = wave winner ----
    PAIRRED(bd, bi, 0x121);  // row_ror:1
    PAIRRED(bd, bi, 0x122);  // row_ror:2
    PAIRRED(bd, bi, 0x124);  // row_ror:4
    PAIRRED(bd, bi, 0x128);  // row_ror:8   -> row reduction
    PAIRRED(bd, bi, 0x142);  // row_bcast15
    PAIRRED(bd, bi, 0x143);  // row_bcast31 -> lane63 = wave reduction
    if (lane == 63) { cndD[par][wv] = bd; cndI[par][wv] = bi; }
    __syncthreads();

    // ---- cross-wave: mirror 4 candidates, 2 pair-DPP steps -> every lane = winner ----
    const int ci = lane & 3;
    float pd = cndD[par][ci];
    int pi = cndI[par][ci];
    PAIRRED(pd, pi, 0x121);  // window 2
    PAIRRED(pd, pi, 0x122);  // window 4 = all 4 candidates
    const int far = __builtin_amdgcn_readfirstlane(pi);
    // coords via uniform load (L1/L2 hit), replaces register scavenging
    const float* pc = px + 3 * (size_t)far;
    cx = pc[0]; cy = pc[1]; cz = pc[2];
    if (tid == 0) { oI[t] = far; oX[t] = cx; oY[t] = cy; oZ[t] = cz; }
    par ^= 1;
  }
  __syncthreads();

  // ---- cooperative flush: LDS -> global ----
  for (int i = tid; i < NS; i += 256) {
    fpsidx[b * NS + i] = oI[i];
    float* o = newxyz + ((size_t)b * NS + i) * 3;
    o[0] = oX[i]; o[1] = oY[i]; o[2] = oZ[i];
  }
}

// ---------------- ball query + group + MLP + maxpool: one block per centroid ----------------
__global__ __launch_bounds__(256)
void sa_kernel(const float* __restrict__ xyz, const float* __restrict__ feat,
               const float* __restrict__ ws, const int* __restrict__ fpsidx,
               const float* __restrict__ newxyz, float* __restrict__ outf) {
  const int bs = blockIdx.x;
  const int b = bs >> 11;
  const int s = bs & (NS - 1);
  const int tid = threadIdx.x;
  const int lane = tid & 63;

  __shared__ __align__(16) unsigned long long cand[CAP];
  __shared__ int cntS;
  __shared__ int sel[NK];
  __shared__ float hA[32 * 69];
  __shared__ float hB[32 * 65];

  const float* px = xyz + (size_t)b * NPTS * 3;
  const float* pf = feat + (size_t)b * NPTS * CIN;
  const size_t srow = (size_t)b * NS + s;
  const float cx = newxyz[srow * 3 + 0];
  const float cy = newxyz[srow * 3 + 1];
  const float cz = newxyz[srow * 3 + 2];

  if (tid == 0) cntS = 0;
  __syncthreads();

  // ---- phase A: ball query + ballot compaction (1 atomic per wave per chunk) ----
  const float ssrc = sq3(cx, cy, cz);
  const float R2F = 0.04f;  // f32 round of f64 0.2**2
  for (int p = tid; p < NPTS; p += 256) {
    float x = px[p * 3 + 0], y = px[p * 3 + 1], z = px[p * 3 + 2];
    float sdst = sq3(x, y, z);
    float dot = __fadd_rn(__fadd_rn(__fmul_rn(cx, x), __fmul_rn(cy, y)), __fmul_rn(cz, z));
    float d = __fsub_rn(__fadd_rn(ssrc, sdst), __fmul_rn(2.0f, dot));
    d = fmaxf(d, 0.0f);
    bool hit = (d <= R2F);
    unsigned long long m = __ballot(hit);
    if (m) {
      int base = 0;
      if (lane == 0) base = atomicAdd(&cntS, __popcll(m));
      base = __shfl(base, 0);
      if (hit) {
        int pos = base + __popcll(m & ((1ull << lane) - 1ull));
        if (pos < CAP)
          cand[pos] = ((unsigned long long)__float_as_uint(d) << 32) | (unsigned long long)(unsigned)p;
      }
    }
  }
  __syncthreads();

  // ---- phase B: parallel rank-select of 32 smallest (keys unique -> exact set) ----
  {
    const int cnt = min(cntS, CAP);
    if (cnt <= 256) {
      unsigned long long k0 = (tid < cnt) ? cand[tid] : ~0ull;
      int r0 = 0;
      int j = 0;
      for (; j + 2 <= cnt; j += 2) {
        ulonglong2 kj = *(const ulonglong2*)&cand[j];   // broadcast reads
        r0 += (kj.x < k0) ? 1 : 0;
        r0 += (kj.y < k0) ? 1 : 0;
      }
      if (j < cnt) r0 += (cand[j] < k0) ? 1 : 0;
      if (tid < cnt) {
        if (r0 < NK) sel[r0] = (int)(k0 & 0xffffffffull);
        if (r0 == 0) {
          for (int q = cnt; q < NK; ++q) sel[q] = (int)(k0 & 0xffffffffull);  // pad w/ nearest
        }
      }
    } else if (cnt <= 512) {
      unsigned long long k0 = cand[tid];
      unsigned long long k1 = (256 + tid < cnt) ? cand[256 + tid] : ~0ull;
      int r0 = 0, r1 = 0;
      int j = 0;
      for (; j + 2 <= cnt; j += 2) {
        ulonglong2 kj = *(const ulonglong2*)&cand[j];
        r0 += (kj.x < k0) ? 1 : 0; r0 += (kj.y < k0) ? 1 : 0;
        r1 += (kj.x < k1) ? 1 : 0; r1 += (kj.y < k1) ? 1 : 0;
      }
      if (j < cnt) { unsigned long long kj = cand[j]; r0 += (kj < k0) ? 1 : 0; r1 += (kj < k1) ? 1 : 0; }
      if (r0 < NK) sel[r0] = (int)(k0 & 0xffffffffull);
      if (256 + tid < cnt && r1 < NK) sel[r1] = (int)(k1 & 0xffffffffull);
    } else {
      unsigned long long k0 = cand[tid];
      unsigned long long k1 = cand[256 + tid];
      unsigned long long k2 = (512 + tid < cnt) ? cand[512 + tid] : ~0ull;
      unsigned long long k3 = (768 + tid < cnt) ? cand[768 + tid] : ~0ull;
      int r0 = 0, r1 = 0, r2 = 0, r3 = 0;
      int j = 0;
      for (; j + 2 <= cnt; j += 2) {
        ulonglong2 kj = *(const ulonglong2*)&cand[j];
        r0 += (kj.x < k0) ? 1 : 0; r0 += (kj.y < k0) ? 1 : 0;
        r1 += (kj.x < k1) ? 1 : 0; r1 += (kj.y < k1) ? 1 : 0;
        r2 += (kj.x < k2) ? 1 : 0; r2 += (kj.y < k2) ? 1 : 0;
        r3 += (kj.x < k3) ? 1 : 0; r3 += (kj.y < k3) ? 1 : 0;
      }
      if (j < cnt) {
        unsigned long long kj = cand[j];
        r0 += (kj < k0) ? 1 : 0; r1 += (kj < k1) ? 1 : 0;
        r2 += (kj < k2) ? 1 : 0; r3 += (kj < k3) ? 1 : 0;
      }
      if (r0 < NK) sel[r0] = (int)(k0 & 0xffffffffull);
      if (r1 < NK) sel[r1] = (int)(k1 & 0xffffffffull);
      if (512 + tid < cnt && r2 < NK) sel[r2] = (int)(k2 & 0xffffffffull);
      if (768 + tid < cnt && r3 < NK) sel[r3] = (int)(k3 & 0xffffffffull);
    }
  }
  __syncthreads();

  // ---- phase C: build h0 = [centered xyz(3) | feat(64)] into hA [32][69] ----
  {
    int kk = tid >> 3, j = tid & 7;
    int ip = sel[kk];
    const float* fr = pf + (size_t)ip * CIN + j * 8;
    float4 a = *(const float4*)(fr);
    float4 c4 = *(const float4*)(fr + 4);
    float* hrow = hA + kk * 69 + 3 + j * 8;
    hrow[0] = a.x;  hrow[1] = a.y;  hrow[2] = a.z;  hrow[3] = a.w;
    hrow[4] = c4.x; hrow[5] = c4.y; hrow[6] = c4.z; hrow[7] = c4.w;
  }
  if (tid < 32) {
    int ip = sel[tid];
    hA[tid * 69 + 0] = px[ip * 3 + 0] - cx;
    hA[tid * 69 + 1] = px[ip * 3 + 1] - cy;
    hA[tid * 69 + 2] = px[ip * 3 + 2] - cz;
  }
  __syncthreads();

  const int k = tid & 31;   // neighbor slot
  const int ob = tid >> 5;  // output-channel block (0..7)

  // ---- layer 1: 67 -> 64 ----
  {
    const float* Wt = ws + WT0_OFF;
    const float* bb = ws + B0_OFF;
    const int o0 = ob * 8;
    float acc[8];
#pragma unroll
    for (int i = 0; i < 8; ++i) acc[i] = bb[o0 + i];
    const float* hrow = hA + k * 69;
    for (int c = 0; c < C0; ++c) {
      float h = hrow[c];
      const float4 w0 = *(const float4*)(Wt + c * H1 + o0);
      const float4 w1 = *(const float4*)(Wt + c * H1 + o0 + 4);
      acc[0] = fmaf(h, w0.x, acc[0]); acc[1] = fmaf(h, w0.y, acc[1]);
      acc[2] = fmaf(h, w0.z, acc[2]); acc[3] = fmaf(h, w0.w, acc[3]);
      acc[4] = fmaf(h, w1.x, acc[4]); acc[5] = fmaf(h, w1.y, acc[5]);
      acc[6] = fmaf(h, w1.z, acc[6]); acc[7] = fmaf(h, w1.w, acc[7]);
    }
    float* orow = hB + k * 65 + o0;
#pragma unroll
    for (int i = 0; i < 8; ++i) orow[i] = fmaxf(acc[i], 0.0f);
  }
  __syncthreads();

  // ---- layer 2: 64 -> 64 (hB -> hA, stride 65) ----
  {
    const float* Wt = ws + WT1_OFF;
    const float* bb = ws + B1_OFF;
    const int o0 = ob * 8;
    float acc[8];
#pragma unroll
    for (int i = 0; i < 8; ++i) acc[i] = bb[o0 + i];
    const float* hrow = hB + k * 65;
    for (int c = 0; c < H1; ++c) {
      float h = hrow[c];
      const float4 w0 = *(const float4*)(Wt + c * H2 + o0);
      const float4 w1 = *(const float4*)(Wt + c * H2 + o0 + 4);
      acc[0] = fmaf(h, w0.x, acc[0]); acc[1] = fmaf(h, w0.y, acc[1]);
      acc[2] = fmaf(h, w0.z, acc[2]); acc[3] = fmaf(h, w0.w, acc[3]);
      acc[4] = fmaf(h, w1.x, acc[4]); acc[5] = fmaf(h, w1.y, acc[5]);
      acc[6] = fmaf(h, w1.z, acc[6]); acc[7] = fmaf(h, w1.w, acc[7]);
    }
    float* orow = hA + k * 65 + o0;
#pragma unroll
    for (int i = 0; i < 8; ++i) orow[i] = fmaxf(acc[i], 0.0f);
  }
  __syncthreads();

  // ---- layer 3: 64 -> 128 + max over neighbors ----
  {
    const float* Wt = ws + WT2_OFF;
    const float* bb = ws + B2_OFF;
    const int o0 = ob * 16;
    float acc[16];
#pragma unroll
    for (int i = 0; i < 16; ++i) acc[i] = bb[o0 + i];
    const float* hrow = hA + k * 65;
    for (int c = 0; c < H2; ++c) {
      float h = hrow[c];
      const float4 w0 = *(const float4*)(Wt + c * H3 + o0);
      const float4 w1 = *(const float4*)(Wt + c * H3 + o0 + 4);
      const float4 w2 = *(const float4*)(Wt + c * H3 + o0 + 8);
      const float4 w3 = *(const float4*)(Wt + c * H3 + o0 + 12);
      acc[0]  = fmaf(h, w0.x, acc[0]);  acc[1]  = fmaf(h, w0.y, acc[1]);
      acc[2]  = fmaf(h, w0.z, acc[2]);  acc[3]  = fmaf(h, w0.w, acc[3]);
      acc[4]  = fmaf(h, w1.x, acc[4]);  acc[5]  = fmaf(h, w1.y, acc[5]);
      acc[6]  = fmaf(h, w1.z, acc[6]);  acc[7]  = fmaf(h, w1.w, acc[7]);
      acc[8]  = fmaf(h, w2.x, acc[8]);  acc[9]  = fmaf(h, w2.y, acc[9]);
      acc[10] = fmaf(h, w2.z, acc[10]); acc[11] = fmaf(h, w2.w, acc[11]);
      acc[12] = fmaf(h, w3.x, acc[12]); acc[13] = fmaf(h, w3.y, acc[13]);
      acc[14] = fmaf(h, w3.z, acc[14]); acc[15] = fmaf(h, w3.w, acc[15]);
    }
#pragma unroll
    for (int i = 0; i < 16; ++i) acc[i] = fmaxf(acc[i], 0.0f);
#pragma unroll
    for (int m = 1; m < 32; m <<= 1) {
#pragma unroll
      for (int i = 0; i < 16; ++i) {
        float o = __shfl_xor(acc[i], m);
        acc[i] = fmaxf(acc[i], o);
      }
    }
    if (k == 0) {
      float* op = outf + srow * H3 + o0;
      *(float4*)(op + 0)  = make_float4(acc[0],  acc[1],  acc[2],  acc[3]);
      *(float4*)(op + 4)  = make_float4(acc[4],  acc[5],  acc[6],  acc[7]);
      *(float4*)(op + 8)  = make_float4(acc[8],  acc[9],  acc[10], acc[11]);
      *(float4*)(op + 12) = make_float4(acc[12], acc[13], acc[14], acc[15]);
    }
  }
}

extern "C" void kernel_launch(void* const* d_in, const int* in_sizes, int n_in,
                              void* d_out, int out_size, void* d_ws, size_t ws_size,
                              hipStream_t stream) {
  const float* xyz  = (const float*)d_in[0];
  const float* feat = (const float*)d_in[1];
  const float* W0 = (const float*)d_in[2];
  const float* g0 = (const float*)d_in[3];
  const float* be0 = (const float*)d_in[4];
  const float* m0 = (const float*)d_in[5];
  const float* v0 = (const float*)d_in[6];
  const float* W1 = (const float*)d_in[7];
  const float* g1 = (const float*)d_in[8];
  const float* be1 = (const float*)d_in[9];
  const float* m1 = (const float*)d_in[10];
  const float* v1 = (const float*)d_in[11];
  const float* W2 = (const float*)d_in[12];
  const float* g2 = (const float*)d_in[13];
  const float* be2 = (const float*)d_in[14];
  const float* m2 = (const float*)d_in[15];
  const float* v2 = (const float*)d_in[16];

  float* out = (float*)d_out;               // [B,S,3] then [B,S,128]
  float* ws = (float*)d_ws;
  int* fpsidx = (int*)(ws + FPS_OFF);
  float* outfeat = out + (size_t)NBATCH * NS * 3;

  fold_kernel<<<(B2_OFF + H3 + 255) / 256, 256, 0, stream>>>(
      W0, g0, be0, m0, v0, W1, g1, be1, m1, v1, W2, g2, be2, m2, v2, ws);
  fps_kernel<<<NBATCH, 256, 0, stream>>>(xyz, out, fpsidx);
  sa_kernel<<<NBATCH * NS, 256, 0, stream>>>(xyz, feat, ws, fpsidx, out, outfeat);
}

// Round 9
// 2690.928 us; speedup vs baseline: 1.2163x; 1.0655x over previous
//
#include <hip/hip_runtime.h>
#include <cstdint>

#define NPTS 8192
#define NBATCH 4
#define NS 2048
#define NK 32
#define CIN 64
#define C0 67   // 3 + 64
#define H1 64
#define H2 64
#define H3 128
#define CAP 1024
#define BIGF 1e10f

// ws layout in floats
#define WT0_OFF 0        // 67*64
#define B0_OFF  4288     // 64
#define WT1_OFF 4352     // 64*64
#define B1_OFF  8448     // 64
#define WT2_OFF 8512     // 64*128
#define B2_OFF  16704    // 128
#define FPS_OFF 16832    // NBATCH*NS ints from here

typedef float f32x2 __attribute__((ext_vector_type(2)));

__device__ __forceinline__ float sq3(float ax, float ay, float az) {
  // exact f32, no contraction: (ax*ax + ay*ay) + az*az
  return __fadd_rn(__fadd_rn(__fmul_rn(ax, ax), __fmul_rn(ay, ay)), __fmul_rn(az, az));
}

// packed 2xf32 ops (VOP3P, IEEE f32 per lane — exact, same as scalar __f*_rn)
__device__ __forceinline__ f32x2 pk_sub(f32x2 a, f32x2 b) {
  f32x2 r;
  asm("v_pk_add_f32 %0, %1, %2 neg_lo:[0,1] neg_hi:[0,1]" : "=v"(r) : "v"(a), "v"(b));
  return r;
}
__device__ __forceinline__ f32x2 pk_mul(f32x2 a, f32x2 b) {
  f32x2 r;
  asm("v_pk_mul_f32 %0, %1, %2" : "=v"(r) : "v"(a), "v"(b));
  return r;
}
__device__ __forceinline__ f32x2 pk_add(f32x2 a, f32x2 b) {
  f32x2 r;
  asm("v_pk_add_f32 %0, %1, %2" : "=v"(r) : "v"(a), "v"(b));
  return r;
}

// Lexicographic (max d, tie -> min idx) pair-combine with a DPP-shuffled copy.
#define PAIRRED(dv, iv, ctrl)                                                          \
  {                                                                                    \
    int _sd = __builtin_amdgcn_update_dpp(__float_as_int(dv), __float_as_int(dv),      \
                                          (ctrl), 0xf, 0xf, false);                    \
    int _si = __builtin_amdgcn_update_dpp((iv), (iv), (ctrl), 0xf, 0xf, false);        \
    float _fd = __int_as_float(_sd);                                                   \
    bool _tk = (_fd > (dv)) || ((_fd == (dv)) && (_si < (iv)));                        \
    (dv) = _tk ? _fd : (dv);                                                           \
    (iv) = _tk ? _si : (iv);                                                           \
  }

// ---------------- fold BN into weights (transposed [c][o]) ----------------
__global__ void fold_kernel(const float* __restrict__ W0, const float* __restrict__ g0, const float* __restrict__ be0, const float* __restrict__ m0, const float* __restrict__ v0,
                            const float* __restrict__ W1, const float* __restrict__ g1, const float* __restrict__ be1, const float* __restrict__ m1, const float* __restrict__ v1,
                            const float* __restrict__ W2, const float* __restrict__ g2, const float* __restrict__ be2, const float* __restrict__ m2, const float* __restrict__ v2,
                            float* __restrict__ ws) {
  int t = blockIdx.x * 256 + threadIdx.x;
  if (t < C0 * H1) {
    int c = t / H1, o = t - c * H1;
    float sc = g0[o] / sqrtf(v0[o] + 1e-5f);
    ws[WT0_OFF + t] = W0[o * C0 + c] * sc;
  } else if (t < B0_OFF + H1) {
    int o = t - B0_OFF;
    float sc = g0[o] / sqrtf(v0[o] + 1e-5f);
    ws[t] = be0[o] - m0[o] * sc;
  } else if (t < WT1_OFF + H1 * H2) {
    int t2 = t - WT1_OFF; int c = t2 / H2, o = t2 - c * H2;
    float sc = g1[o] / sqrtf(v1[o] + 1e-5f);
    ws[t] = W1[o * H1 + c] * sc;
  } else if (t < B1_OFF + H2) {
    int o = t - B1_OFF;
    float sc = g1[o] / sqrtf(v1[o] + 1e-5f);
    ws[t] = be1[o] - m1[o] * sc;
  } else if (t < WT2_OFF + H2 * H3) {
    int t2 = t - WT2_OFF; int c = t2 / H3, o = t2 - c * H3;
    float sc = g2[o] / sqrtf(v2[o] + 1e-5f);
    ws[t] = W2[o * H2 + c] * sc;
  } else if (t < B2_OFF + H3) {
    int o = t - B2_OFF;
    float sc = g2[o] / sqrtf(v2[o] + 1e-5f);
    ws[t] = be2[o] - m2[o] * sc;
  }
}

// ---------------- FPS: one block per batch, 256 threads, 32 pts/thread ----------------
// Packed-f32 distance update (2 pts/inst); (d,i) pair-DPP reduces; winner coords
// via broadcast ds_read_b128 from an LDS mirror of all points; direct global out.
__global__ __launch_bounds__(256, 1)
void fps_kernel(const float* __restrict__ xyz, float* __restrict__ newxyz, int* __restrict__ fpsidx) {
  const int b = blockIdx.x;
  const float* px = xyz + (size_t)b * NPTS * 3;
  const int tid = threadIdx.x;
  const int lane = tid & 63;
  const int wv = tid >> 6;   // 0..3

  __shared__ __align__(16) float lco[NPTS * 4];   // 128 KB point-coords mirror
  __shared__ __align__(8) float cnd[2][4][2];     // [parity][wave][{d, idx_bits}]

  f32x2 X2[16], Y2[16], Z2[16], D2[16];
#pragma unroll
  for (int jj = 0; jj < 16; ++jj) {
    int p0 = tid * 32 + 2 * jj;
    float x0 = px[p0 * 3 + 0], y0 = px[p0 * 3 + 1], z0 = px[p0 * 3 + 2];
    float x1 = px[p0 * 3 + 3], y1 = px[p0 * 3 + 4], z1 = px[p0 * 3 + 5];
    X2[jj][0] = x0; X2[jj][1] = x1;
    Y2[jj][0] = y0; Y2[jj][1] = y1;
    Z2[jj][0] = z0; Z2[jj][1] = z1;
    D2[jj][0] = BIGF; D2[jj][1] = BIGF;
    *(float4*)&lco[(size_t)p0 * 4]       = make_float4(x0, y0, z0, 0.0f);
    *(float4*)&lco[(size_t)(p0 + 1) * 4] = make_float4(x1, y1, z1, 0.0f);
  }

  float cx = px[0], cy = px[1], cz = px[2];
  if (tid == 0) {
    fpsidx[b * NS] = 0;
    float* o = newxyz + (size_t)b * NS * 3;
    o[0] = cx; o[1] = cy; o[2] = cz;
  }
  __syncthreads();   // lco ready

  int par = 0;
  for (int t = 1; t < NS; ++t) {
    f32x2 cpx, cpy, cpz;
    cpx[0] = cx; cpx[1] = cx;
    cpy[0] = cy; cpy[1] = cy;
    cpz[0] = cz; cpz[1] = cz;
    // ---- packed min-dist update + inline (d,idx) argmax (exact f32, ref order) ----
    float bd = -1.0f; int bi = 0;
#pragma unroll
    for (int jj = 0; jj < 16; ++jj) {
      f32x2 dx = pk_sub(X2[jj], cpx);
      f32x2 dy = pk_sub(Y2[jj], cpy);
      f32x2 dz = pk_sub(Z2[jj], cpz);
      f32x2 xx = pk_mul(dx, dx);
      f32x2 yy = pk_mul(dy, dy);
      f32x2 ss = pk_add(xx, yy);
      f32x2 zz = pk_mul(dz, dz);
      f32x2 dd = pk_add(ss, zz);
      float n0 = fminf(D2[jj][0], dd[0]);
      float n1 = fminf(D2[jj][1], dd[1]);
      D2[jj][0] = n0; D2[jj][1] = n1;
      bool g0 = n0 > bd;               // strict >, ascending order -> first index kept
      bd = g0 ? n0 : bd;
      bi = g0 ? (tid * 32 + 2 * jj) : bi;
      bool g1 = n1 > bd;
      bd = g1 ? n1 : bd;
      bi = g1 ? (tid * 32 + 2 * jj + 1) : bi;
    }
    // ---- wave pair-argmax via DPP; lane63 = wave winner ----
    PAIRRED(bd, bi, 0x121);  // row_ror:1
    PAIRRED(bd, bi, 0x122);  // row_ror:2
    PAIRRED(bd, bi, 0x124);  // row_ror:4
    PAIRRED(bd, bi, 0x128);  // row_ror:8
    PAIRRED(bd, bi, 0x142);  // row_bcast15
    PAIRRED(bd, bi, 0x143);  // row_bcast31 -> lane63 = wave reduction
    if (lane == 63) {
      cnd[par][wv][0] = bd;
      cnd[par][wv][1] = __int_as_float(bi);
    }
    __syncthreads();

    // ---- cross-wave: mirror 4 candidates, 2 pair-DPP steps -> all lanes = winner ----
    const int ci = lane & 3;
    f32x2 cc = *(const f32x2*)&cnd[par][ci][0];
    float pd = cc[0];
    int pi = __float_as_int(cc[1]);
    PAIRRED(pd, pi, 0x121);
    PAIRRED(pd, pi, 0x122);
    const int far = __builtin_amdgcn_readfirstlane(pi);
    // coords via broadcast LDS read (no L2 on the chain)
    float4 c4 = *(const float4*)&lco[(size_t)far * 4];
    cx = c4.x; cy = c4.y; cz = c4.z;
    if (tid == 0) {
      fpsidx[b * NS + t] = far;
      float* o = newxyz + ((size_t)b * NS + t) * 3;
      o[0] = cx; o[1] = cy; o[2] = cz;
    }
    par ^= 1;
  }
}

// ---------------- ball query + group + MLP + maxpool: one block per centroid ----------------
__global__ __launch_bounds__(256)
void sa_kernel(const float* __restrict__ xyz, const float* __restrict__ feat,
               const float* __restrict__ ws, const int* __restrict__ fpsidx,
               const float* __restrict__ newxyz, float* __restrict__ outf) {
  const int bs = blockIdx.x;
  const int b = bs >> 11;
  const int s = bs & (NS - 1);
  const int tid = threadIdx.x;
  const int lane = tid & 63;

  __shared__ __align__(16) unsigned long long cand[CAP];
  __shared__ int cntS;
  __shared__ int sel[NK];
  __shared__ float hA[32 * 69];
  __shared__ float hB[32 * 65];

  const float* px = xyz + (size_t)b * NPTS * 3;
  const float* pf = feat + (size_t)b * NPTS * CIN;
  const size_t srow = (size_t)b * NS + s;
  const float cx = newxyz[srow * 3 + 0];
  const float cy = newxyz[srow * 3 + 1];
  const float cz = newxyz[srow * 3 + 2];

  if (tid == 0) cntS = 0;
  __syncthreads();

  // ---- phase A: ball query + ballot compaction (1 atomic per wave per chunk) ----
  const float ssrc = sq3(cx, cy, cz);
  const float R2F = 0.04f;  // f32 round of f64 0.2**2
  for (int p = tid; p < NPTS; p += 256) {
    float x = px[p * 3 + 0], y = px[p * 3 + 1], z = px[p * 3 + 2];
    float sdst = sq3(x, y, z);
    float dot = __fadd_rn(__fadd_rn(__fmul_rn(cx, x), __fmul_rn(cy, y)), __fmul_rn(cz, z));
    float d = __fsub_rn(__fadd_rn(ssrc, sdst), __fmul_rn(2.0f, dot));
    d = fmaxf(d, 0.0f);
    bool hit = (d <= R2F);
    unsigned long long m = __ballot(hit);
    if (m) {
      int base = 0;
      if (lane == 0) base = atomicAdd(&cntS, __popcll(m));
      base = __shfl(base, 0);
      if (hit) {
        int pos = base + __popcll(m & ((1ull << lane) - 1ull));
        if (pos < CAP)
          cand[pos] = ((unsigned long long)__float_as_uint(d) << 32) | (unsigned long long)(unsigned)p;
      }
    }
  }
  __syncthreads();

  // ---- phase B: parallel rank-select of 32 smallest (keys unique -> exact set) ----
  {
    const int cnt = min(cntS, CAP);
    if (cnt <= 256) {
      unsigned long long k0 = (tid < cnt) ? cand[tid] : ~0ull;
      int r0 = 0;
      int j = 0;
      for (; j + 2 <= cnt; j += 2) {
        ulonglong2 kj = *(const ulonglong2*)&cand[j];   // broadcast reads
        r0 += (kj.x < k0) ? 1 : 0;
        r0 += (kj.y < k0) ? 1 : 0;
      }
      if (j < cnt) r0 += (cand[j] < k0) ? 1 : 0;
      if (tid < cnt) {
        if (r0 < NK) sel[r0] = (int)(k0 & 0xffffffffull);
        if (r0 == 0) {
          for (int q = cnt; q < NK; ++q) sel[q] = (int)(k0 & 0xffffffffull);  // pad w/ nearest
        }
      }
    } else if (cnt <= 512) {
      unsigned long long k0 = cand[tid];
      unsigned long long k1 = (256 + tid < cnt) ? cand[256 + tid] : ~0ull;
      int r0 = 0, r1 = 0;
      int j = 0;
      for (; j + 2 <= cnt; j += 2) {
        ulonglong2 kj = *(const ulonglong2*)&cand[j];
        r0 += (kj.x < k0) ? 1 : 0; r0 += (kj.y < k0) ? 1 : 0;
        r1 += (kj.x < k1) ? 1 : 0; r1 += (kj.y < k1) ? 1 : 0;
      }
      if (j < cnt) { unsigned long long kj = cand[j]; r0 += (kj < k0) ? 1 : 0; r1 += (kj < k1) ? 1 : 0; }
      if (r0 < NK) sel[r0] = (int)(k0 & 0xffffffffull);
      if (256 + tid < cnt && r1 < NK) sel[r1] = (int)(k1 & 0xffffffffull);
    } else {
      unsigned long long k0 = cand[tid];
      unsigned long long k1 = cand[256 + tid];
      unsigned long long k2 = (512 + tid < cnt) ? cand[512 + tid] : ~0ull;
      unsigned long long k3 = (768 + tid < cnt) ? cand[768 + tid] : ~0ull;
      int r0 = 0, r1 = 0, r2 = 0, r3 = 0;
      int j = 0;
      for (; j + 2 <= cnt; j += 2) {
        ulonglong2 kj = *(const ulonglong2*)&cand[j];
        r0 += (kj.x < k0) ? 1 : 0; r0 += (kj.y < k0) ? 1 : 0;
        r1 += (kj.x < k1) ? 1 : 0; r1 += (kj.y < k1) ? 1 : 0;
        r2 += (kj.x < k2) ? 1 : 0; r2 += (kj.y < k2) ? 1 : 0;
        r3 += (kj.x < k3) ? 1 : 0; r3 += (kj.y < k3) ? 1 : 0;
      }
      if (j < cnt) {
        unsigned long long kj = cand[j];
        r0 += (kj < k0) ? 1 : 0; r1 += (kj < k1) ? 1 : 0;
        r2 += (kj < k2) ? 1 : 0; r3 += (kj < k3) ? 1 : 0;
      }
      if (r0 < NK) sel[r0] = (int)(k0 & 0xffffffffull);
      if (r1 < NK) sel[r1] = (int)(k1 & 0xffffffffull);
      if (512 + tid < cnt && r2 < NK) sel[r2] = (int)(k2 & 0xffffffffull);
      if (768 + tid < cnt && r3 < NK) sel[r3] = (int)(k3 & 0xffffffffull);
    }
  }
  __syncthreads();

  // ---- phase C: build h0 = [centered xyz(3) | feat(64)] into hA [32][69] ----
  {
    int kk = tid >> 3, j = tid & 7;
    int ip = sel[kk];
    const float* fr = pf + (size_t)ip * CIN + j * 8;
    float4 a = *(const float4*)(fr);
    float4 c4 = *(const float4*)(fr + 4);
    float* hrow = hA + kk * 69 + 3 + j * 8;
    hrow[0] = a.x;  hrow[1] = a.y;  hrow[2] = a.z;  hrow[3] = a.w;
    hrow[4] = c4.x; hrow[5] = c4.y; hrow[6] = c4.z; hrow[7] = c4.w;
  }
  if (tid < 32) {
    int ip = sel[tid];
    hA[tid * 69 + 0] = px[ip * 3 + 0] - cx;
    hA[tid * 69 + 1] = px[ip * 3 + 1] - cy;
    hA[tid * 69 + 2] = px[ip * 3 + 2] - cz;
  }
  __syncthreads();

  const int k = tid & 31;   // neighbor slot
  const int ob = tid >> 5;  // output-channel block (0..7)

  // ---- layer 1: 67 -> 64 ----
  {
    const float* Wt = ws + WT0_OFF;
    const float* bb = ws + B0_OFF;
    const int o0 = ob * 8;
    float acc[8];
#pragma unroll
    for (int i = 0; i < 8; ++i) acc[i] = bb[o0 + i];
    const float* hrow = hA + k * 69;
    for (int c = 0; c < C0; ++c) {
      float h = hrow[c];
      const float4 w0 = *(const float4*)(Wt + c * H1 + o0);
      const float4 w1 = *(const float4*)(Wt + c * H1 + o0 + 4);
      acc[0] = fmaf(h, w0.x, acc[0]); acc[1] = fmaf(h, w0.y, acc[1]);
      acc[2] = fmaf(h, w0.z, acc[2]); acc[3] = fmaf(h, w0.w, acc[3]);
      acc[4] = fmaf(h, w1.x, acc[4]); acc[5] = fmaf(h, w1.y, acc[5]);
      acc[6] = fmaf(h, w1.z, acc[6]); acc[7] = fmaf(h, w1.w, acc[7]);
    }
    float* orow = hB + k * 65 + o0;
#pragma unroll
    for (int i = 0; i < 8; ++i) orow[i] = fmaxf(acc[i], 0.0f);
  }
  __syncthreads();

  // ---- layer 2: 64 -> 64 (hB -> hA, stride 65) ----
  {
    const float* Wt = ws + WT1_OFF;
    const float* bb = ws + B1_OFF;
    const int o0 = ob * 8;
    float acc[8];
#pragma unroll
    for (int i = 0; i < 8; ++i) acc[i] = bb[o0 + i];
    const float* hrow = hB + k * 65;
    for (int c = 0; c < H1; ++c) {
      float h = hrow[c];
      const float4 w0 = *(const float4*)(Wt + c * H2 + o0);
      const float4 w1 = *(const float4*)(Wt + c * H2 + o0 + 4);
      acc[0] = fmaf(h, w0.x, acc[0]); acc[1] = fmaf(h, w0.y, acc[1]);
      acc[2] = fmaf(h, w0.z, acc[2]); acc[3] = fmaf(h, w0.w, acc[3]);
      acc[4] = fmaf(h, w1.x, acc[4]); acc[5] = fmaf(h, w1.y, acc[5]);
      acc[6] = fmaf(h, w1.z, acc[6]); acc[7] = fmaf(h, w1.w, acc[7]);
    }
    float* orow = hA + k * 65 + o0;
#pragma unroll
    for (int i = 0; i < 8; ++i) orow[i] = fmaxf(acc[i], 0.0f);
  }
  __syncthreads();

  // ---- layer 3: 64 -> 128 + max over neighbors ----
  {
    const float* Wt = ws + WT2_OFF;
    const float* bb = ws + B2_OFF;
    const int o0 = ob * 16;
    float acc[16];
#pragma unroll
    for (int i = 0; i < 16; ++i) acc[i] = bb[o0 + i];
    const float* hrow = hA + k * 65;
    for (int c = 0; c < H2; ++c) {
      float h = hrow[c];
      const float4 w0 = *(const float4*)(Wt + c * H3 + o0);
      const float4 w1 = *(const float4*)(Wt + c * H3 + o0 + 4);
      const float4 w2 = *(const float4*)(Wt + c * H3 + o0 + 8);
      const float4 w3 = *(const float4*)(Wt + c * H3 + o0 + 12);
      acc[0]  = fmaf(h, w0.x, acc[0]);  acc[1]  = fmaf(h, w0.y, acc[1]);
      acc[2]  = fmaf(h, w0.z, acc[2]);  acc[3]  = fmaf(h, w0.w, acc[3]);
      acc[4]  = fmaf(h, w1.x, acc[4]);  acc[5]  = fmaf(h, w1.y, acc[5]);
      acc[6]  = fmaf(h, w1.z, acc[6]);  acc[7]  = fmaf(h, w1.w, acc[7]);
      acc[8]  = fmaf(h, w2.x, acc[8]);  acc[9]  = fmaf(h, w2.y, acc[9]);
      acc[10] = fmaf(h, w2.z, acc[10]); acc[11] = fmaf(h, w2.w, acc[11]);
      acc[12] = fmaf(h, w3.x, acc[12]); acc[13] = fmaf(h, w3.y, acc[13]);
      acc[14] = fmaf(h, w3.z, acc[14]); acc[15] = fmaf(h, w3.w, acc[15]);
    }
#pragma unroll
    for (int i = 0; i < 16; ++i) acc[i] = fmaxf(acc[i], 0.0f);
#pragma unroll
    for (int m = 1; m < 32; m <<= 1) {
#pragma unroll
      for (int i = 0; i < 16; ++i) {
        float o = __shfl_xor(acc[i], m);
        acc[i] = fmaxf(acc[i], o);
      }
    }
    if (k == 0) {
      float* op = outf + srow * H3 + o0;
      *(float4*)(op + 0)  = make_float4(acc[0],  acc[1],  acc[2],  acc[3]);
      *(float4*)(op + 4)  = make_float4(acc[4],  acc[5],  acc[6],  acc[7]);
      *(float4*)(op + 8)  = make_float4(acc[8],  acc[9],  acc[10], acc[11]);
      *(float4*)(op + 12) = make_float4(acc[12], acc[13], acc[14], acc[15]);
    }
  }
}

extern "C" void kernel_launch(void* const* d_in, const int* in_sizes, int n_in,
                              void* d_out, int out_size, void* d_ws, size_t ws_size,
                              hipStream_t stream) {
  const float* xyz  = (const float*)d_in[0];
  const float* feat = (const float*)d_in[1];
  const float* W0 = (const float*)d_in[2];
  const float* g0 = (const float*)d_in[3];
  const float* be0 = (const float*)d_in[4];
  const float* m0 = (const float*)d_in[5];
  const float* v0 = (const float*)d_in[6];
  const float* W1 = (const float*)d_in[7];
  const float* g1 = (const float*)d_in[8];
  const float* be1 = (const float*)d_in[9];
  const float* m1 = (const float*)d_in[10];
  const float* v1 = (const float*)d_in[11];
  const float* W2 = (const float*)d_in[12];
  const float* g2 = (const float*)d_in[13];
  const float* be2 = (const float*)d_in[14];
  const float* m2 = (const float*)d_in[15];
  const float* v2 = (const float*)d_in[16];

  float* out = (float*)d_out;               // [B,S,3] then [B,S,128]
  float* ws = (float*)d_ws;
  int* fpsidx = (int*)(ws + FPS_OFF);
  float* outfeat = out + (size_t)NBATCH * NS * 3;

  fold_kernel<<<(B2_OFF + H3 + 255) / 256, 256, 0, stream>>>(
      W0, g0, be0, m0, v0, W1, g1, be1, m1, v1, W2, g2, be2, m2, v2, ws);
  fps_kernel<<<NBATCH, 256, 0, stream>>>(xyz, out, fpsidx);
  sa_kernel<<<NBATCH * NS, 256, 0, stream>>>(xyz, feat, ws, fpsidx, out, outfeat);
}